// Round 1
// baseline (246.582 us; speedup 1.0000x reference)
//
#include <hip/hip_runtime.h>

// CubicHermite2d: B=32, N=1024, axes are arange(N) => uniform knots, dx=1,
// searchsorted(axis[1:-1], q) == floor(q) for the value it produces.
//
// out[b,k,p] = h0(ty)*u0 + h1(ty)*(s1-s0) + h2(ty)*u1 + h3(ty)*(s2-s1)
//   where Iy = floor(ys[k]), ty = ys[k]-Iy,
//         s_r = signal[b, Iy+r, p]               (r = 0..2)
//         u_r = x-Hermite of signal row (Iy+r) at xs[p]  (r = 0..1):
//               Ix = floor(xs[p]), tx = xs[p]-Ix,
//               u = h0*a0 + h1*(a1-a0) + h2*a1 + h3*(a2-a1),
//               a_j = signal[b, Iy+r, Ix+j]
//
// Fully fused: one block per (b,k); 3 signal rows (12 KB) staged in LDS.

#define NGRID 1024
#define BATCH 32

__global__ __launch_bounds__(256) void hermite2d_fused(
    const float* __restrict__ signal,   // [B, N, N]
    const float* __restrict__ xs,       // [N]
    const float* __restrict__ ys,       // [N]
    float* __restrict__ out)            // [B, N(k), N(p)]
{
    const int k = blockIdx.x;   // y-query index
    const int b = blockIdx.y;   // batch

    __shared__ float row0[NGRID];
    __shared__ float row1[NGRID];
    __shared__ float row2[NGRID];

    // --- y-direction coefficients (wave-uniform) ---
    const float qy = ys[k];
    int Iy = (int)floorf(qy);
    if (Iy < 0) Iy = 0;
    if (Iy > NGRID - 3) Iy = NGRID - 3;
    const float ty  = qy - (float)Iy;
    const float ty2 = ty * ty;
    const float ty3 = ty2 * ty;
    const float h0y = 1.0f - 3.0f * ty2 + 2.0f * ty3;
    const float h1y = ty - 2.0f * ty2 + ty3;
    const float h2y = 3.0f * ty2 - 2.0f * ty3;
    const float h3y = ty3 - ty2;

    // --- stage rows Iy..Iy+2 into LDS (float4 coalesced) ---
    const float4* src4 = (const float4*)(signal + ((size_t)b * NGRID + (size_t)Iy) * NGRID);
    float4* r0 = (float4*)row0;
    float4* r1 = (float4*)row1;
    float4* r2 = (float4*)row2;
    const int nv = NGRID / 4;  // 256 float4 per row
    {
        const int i = threadIdx.x;  // blockDim.x == 256 == nv
        r0[i] = src4[i];
        r1[i] = src4[i + nv];
        r2[i] = src4[i + 2 * nv];
    }
    __syncthreads();

    float* orow = out + ((size_t)b * NGRID + (size_t)k) * NGRID;

    #pragma unroll
    for (int pp = 0; pp < NGRID / 256; ++pp) {
        const int p = threadIdx.x + pp * 256;

        const float qx = xs[p];
        int Ix = (int)floorf(qx);
        if (Ix < 0) Ix = 0;
        if (Ix > NGRID - 3) Ix = NGRID - 3;
        const float tx = qx - (float)Ix;
        const float t2 = tx * tx;
        const float t3 = t2 * tx;
        const float h0 = 1.0f - 3.0f * t2 + 2.0f * t3;
        const float h1 = tx - 2.0f * t2 + t3;
        const float h2 = 3.0f * t2 - 2.0f * t3;
        const float h3 = t3 - t2;

        // x-interp of rows Iy and Iy+1 at xs[p]
        const float a0 = row0[Ix], a1 = row0[Ix + 1], a2 = row0[Ix + 2];
        const float u0 = h0 * a0 + h1 * (a1 - a0) + h2 * a1 + h3 * (a2 - a1);
        const float b0 = row1[Ix], b1 = row1[Ix + 1], b2 = row1[Ix + 2];
        const float u1 = h0 * b0 + h1 * (b1 - b0) + h2 * b1 + h3 * (b2 - b1);

        // y-direction combine with raw-signal slopes at column p
        const float s0 = row0[p], s1 = row1[p], s2 = row2[p];
        orow[p] = h0y * u0 + h1y * (s1 - s0) + h2y * u1 + h3y * (s2 - s1);
    }
}

extern "C" void kernel_launch(void* const* d_in, const int* in_sizes, int n_in,
                              void* d_out, int out_size, void* d_ws, size_t ws_size,
                              hipStream_t stream) {
    // inputs: 0=xaxis[N], 1=yaxis[N], 2=signal[B,N,N], 3=xs[N], 4=ys[N] (all f32)
    const float* signal = (const float*)d_in[2];
    const float* xs     = (const float*)d_in[3];
    const float* ys     = (const float*)d_in[4];
    float* out          = (float*)d_out;

    dim3 grid(NGRID, BATCH);
    hermite2d_fused<<<grid, 256, 0, stream>>>(signal, xs, ys, out);
}

// Round 2
// 239.268 us; speedup vs baseline: 1.0306x; 1.0306x over previous
//
#include <hip/hip_runtime.h>

// CubicHermite2d: B=32, N=1024, axes are arange(N) => uniform knots, dx=1.
//
// out[b,k,p] = h0y*u0 + h1y*(s1-s0) + h2y*u1 + h3y*(s2-s1)
//   u_r = Hermite_x(row_{Iy+r})(xs[p]),  s_r = signal[b,Iy+r,p]
//
// Key optimization (R1): Hermite_x is LINEAR in the row, and h0y/h2y are
// block-uniform, so  h0y*u0 + h2y*u1 = Hermite_x(h0y*row0 + h2y*row1).
// => stage only ONE combined row in LDS -> 3 random gathers/output, not 6.
// Column terms s0..s2 stay in the loading thread's registers (float4/thread),
// so row2 never touches LDS. LDS: 12 KB -> 4 KB per block.
//
// x-weights folded: u = w0*c0 + w1*c1 + w2*c2,
//   w0 = 1 - t - t^2 + t^3,  w1 = t + 2t^2 - 2t^3,  w2 = t^3 - t^2.

#define NGRID 1024
#define BATCH 32

__global__ __launch_bounds__(256) void hermite2d_fused(
    const float* __restrict__ signal,   // [B, N, N]
    const float* __restrict__ xs,       // [N]
    const float* __restrict__ ys,       // [N]
    float* __restrict__ out)            // [B, N(k), N(p)]
{
    const int k = blockIdx.x;   // y-query index
    const int b = blockIdx.y;   // batch
    const int t = threadIdx.x;  // 256 threads; each owns columns 4t..4t+3

    __shared__ float crow[NGRID];       // h0y*row0 + h2y*row1

    // --- y-direction coefficients (block-uniform) ---
    const float qy = ys[k];
    int Iy = (int)floorf(qy);
    if (Iy < 0) Iy = 0;
    if (Iy > NGRID - 3) Iy = NGRID - 3;
    const float ty  = qy - (float)Iy;
    const float ty2 = ty * ty;
    const float ty3 = ty2 * ty;
    const float h0y = 1.0f - 3.0f * ty2 + 2.0f * ty3;
    const float h1y = ty - 2.0f * ty2 + ty3;
    const float h2y = 3.0f * ty2 - 2.0f * ty3;
    const float h3y = ty3 - ty2;

    // --- load 3 rows (float4 per thread), build combined row + column part ---
    const float4* src4 = (const float4*)(signal + ((size_t)b * NGRID + (size_t)Iy) * NGRID);
    const float4 r0 = src4[t];
    const float4 r1 = src4[t + NGRID / 4];
    const float4 r2 = src4[t + NGRID / 2];

    float4 c;
    c.x = h0y * r0.x + h2y * r1.x;
    c.y = h0y * r0.y + h2y * r1.y;
    c.z = h0y * r0.z + h2y * r1.z;
    c.w = h0y * r0.w + h2y * r1.w;
    ((float4*)crow)[t] = c;

    float colp[4];
    colp[0] = h1y * (r1.x - r0.x) + h3y * (r2.x - r1.x);
    colp[1] = h1y * (r1.y - r0.y) + h3y * (r2.y - r1.y);
    colp[2] = h1y * (r1.z - r0.z) + h3y * (r2.z - r1.z);
    colp[3] = h1y * (r1.w - r0.w) + h3y * (r2.w - r1.w);

    const float4 q4 = ((const float4*)xs)[t];
    const float qx[4] = { q4.x, q4.y, q4.z, q4.w };

    __syncthreads();

    // --- x-interp of the combined row + add column part ---
    float4 res;
    float* resp = (float*)&res;
    #pragma unroll
    for (int j = 0; j < 4; ++j) {
        const float q = qx[j];
        int Ix = (int)floorf(q);
        if (Ix < 0) Ix = 0;
        if (Ix > NGRID - 3) Ix = NGRID - 3;
        const float tx = q - (float)Ix;
        const float t2 = tx * tx;
        const float t3 = t2 * tx;
        const float w0 = 1.0f - tx - t2 + t3;
        const float w1 = tx + 2.0f * (t2 - t3);
        const float w2 = t3 - t2;
        const float c0 = crow[Ix];
        const float c1 = crow[Ix + 1];
        const float c2 = crow[Ix + 2];
        resp[j] = w0 * c0 + w1 * c1 + w2 * c2 + colp[j];
    }

    float4* orow4 = (float4*)(out + ((size_t)b * NGRID + (size_t)k) * NGRID);
    orow4[t] = res;
}

extern "C" void kernel_launch(void* const* d_in, const int* in_sizes, int n_in,
                              void* d_out, int out_size, void* d_ws, size_t ws_size,
                              hipStream_t stream) {
    // inputs: 0=xaxis[N], 1=yaxis[N], 2=signal[B,N,N], 3=xs[N], 4=ys[N] (all f32)
    const float* signal = (const float*)d_in[2];
    const float* xs     = (const float*)d_in[3];
    const float* ys     = (const float*)d_in[4];
    float* out          = (float*)d_out;

    dim3 grid(NGRID, BATCH);
    hermite2d_fused<<<grid, 256, 0, stream>>>(signal, xs, ys, out);
}